// Round 20
// baseline (1301.937 us; speedup 1.0000x reference)
//
#include <hip/hip_runtime.h>
#include <hip/hip_bf16.h>
#include <math.h>

#define BATCH 256
#define LAT 100
#define NCLS 10
#define CIN0 110
#define C1 512
#define C2 256
#define C3 128
#define NCH 3
#define EPS 1e-5f
#define NCOPY 8

typedef __hip_bfloat16 bf16;
typedef short bf16x8 __attribute__((ext_vector_type(8)));
typedef float f32x4 __attribute__((ext_vector_type(4)));

__device__ __forceinline__ float b2f(bf16 v) { return __bfloat162float(v); }
__device__ __forceinline__ bf16 f2b(float v) { return __float2bfloat16(v); }
__device__ __forceinline__ float s2f(short s) {
    unsigned u = ((unsigned)(unsigned short)s) << 16;
    return __builtin_bit_cast(float, u);
}
__device__ __forceinline__ short f2s(float f) {
    bf16 b = __float2bfloat16(f);
    return *(short*)&b;
}

// ======== INTERLEAVED complex channel layout everywhere ========
#define NB_W1 14336
#define NB_W2 32768
#define NB_W3 8192
#define NB_W4 256
#define NB_X0 224
#define NB_Z  36     // zero the stat copies (143360 B)

__device__ __forceinline__ void w1prep_body(const float* wr, const float* wi, bf16* B, int idx) {
    if (idx >= 16384 * 224) return;
    int n = idx / 224, k = idx - n * 224;
    int p = n >> 10;
    int c = (n & 1023) >> 1;
    int part = n & 1;
    int pk = k >= 112; int ci = k - pk * 112;
    float v = 0.f;
    if (ci < CIN0) {
        size_t widx = ((size_t)ci * C1 + c) * 16 + p;
        float vr = wr[widx], vi = wi[widx];
        v = (part == 0) ? (pk ? -vi : vr) : (pk ? vr : vi);
    }
    B[idx] = f2b(v);
}

template<int CIN, int N>
__device__ __forceinline__ void wprep_panel_body(const float* wr, const float* wi, bf16* W,
                                                 size_t idx) {
    constexpr int TWOK = 8 * CIN, C2I = 2 * CIN;
    size_t per_cls = (size_t)2 * N * TWOK;
    if (idx >= 4 * per_cls) return;
    int cls = (int)(idx / per_cls);
    size_t r = idx - (size_t)cls * per_cls;
    size_t chunk_nb = (size_t)TWOK * 128;
    int nb = (int)(r / chunk_nb);
    int r2 = (int)(r - (size_t)nb * chunk_nb);
    int kb = r2 >> 12;
    int w = r2 & 4095;
    int f = w >> 9;
    int l = (w >> 3) & 63;
    int j = w & 7;
    int n_virt = nb * 128 + (f >> 2) * 64 + (f & 3) * 16 + (l & 15);
    int k = kb * 32 + (l >> 4) * 8 + j;
    int c = n_virt >> 1, part = n_virt & 1;
    int t = k / C2I;
    int q = k & (C2I - 1);
    int ci = q >> 1, p = q & 1;
    int py = cls >> 1, px = cls & 1;
    int a = t >> 1, e = t & 1;
    int kh = py ? (a ? 2 : 0) : (a ? 3 : 1);
    int kw = px ? (e ? 2 : 0) : (e ? 3 : 1);
    size_t widx = ((size_t)ci * N + c) * 16 + kh * 4 + kw;
    float vr = wr[widx], vi = wi[widx];
    float v = (part == 0) ? (p ? -vi : vr) : (p ? vr : vi);
    W[idx] = f2b(v);
}

__device__ __forceinline__ void wprep4_body(const float* wr, const float* wi, bf16* W, int idx) {
    if (idx >= 65536) return;
    int cls = idx >> 14, rem = idx & 16383;
    int py = cls >> 1, px = cls & 1;
    int n = rem >> 10, k = rem & 1023;
    float v = 0.f;
    if (n < NCH) {
        int t = k >> 8, q = k & 255;
        int ci = q >> 1, p = q & 1;
        int a = t >> 1, e = t & 1;
        int kh = py ? (a ? 2 : 0) : (a ? 3 : 1);
        int kw = px ? (e ? 2 : 0) : (e ? 3 : 1);
        size_t widx = ((size_t)ci * NCH + n) * 16 + kh * 4 + kw;
        v = p ? -wi[widx] : wr[widx];
    }
    W[idx] = f2b(v);
}

__device__ __forceinline__ void x0_body(const float* nre, const float* nim,
                                        const int* labels, const float* emb,
                                        bf16* A, int idx) {
    if (idx >= BATCH * 224) return;
    int b = idx / 224, k = idx - b * 224;
    int p = k >= 112; int ci = k - p * 112;
    float v = 0.f;
    if (ci < CIN0) {
        if (!p) v = (ci < LAT) ? nre[b * LAT + ci] : emb[labels[b] * NCLS + (ci - LAT)];
        else    v = (ci < LAT) ? nim[b * LAT + ci] : 0.f;
    }
    A[idx] = f2b(v);
}

__global__ void prep_combined(const float* __restrict__ w1r, const float* __restrict__ w1i,
                              const float* __restrict__ w2r, const float* __restrict__ w2i,
                              const float* __restrict__ w3r, const float* __restrict__ w3i,
                              const float* __restrict__ w4r, const float* __restrict__ w4i,
                              const float* __restrict__ nre, const float* __restrict__ nim,
                              const int* __restrict__ labels, const float* __restrict__ emb,
                              bf16* __restrict__ B1, bf16* __restrict__ W2all,
                              bf16* __restrict__ W3all, bf16* __restrict__ W4all,
                              bf16* __restrict__ x0bf, float* __restrict__ Szero) {
    int bid = blockIdx.x;
    if (bid < NB_W1) {
        w1prep_body(w1r, w1i, B1, bid * 256 + threadIdx.x);
    } else if (bid < NB_W1 + NB_W2) {
        wprep_panel_body<C1, C2>(w2r, w2i, W2all, (size_t)(bid - NB_W1) * 256 + threadIdx.x);
    } else if (bid < NB_W1 + NB_W2 + NB_W3) {
        wprep_panel_body<C2, C3>(w3r, w3i, W3all, (size_t)(bid - NB_W1 - NB_W2) * 256 + threadIdx.x);
    } else if (bid < NB_W1 + NB_W2 + NB_W3 + NB_W4) {
        wprep4_body(w4r, w4i, W4all, (bid - NB_W1 - NB_W2 - NB_W3) * 256 + threadIdx.x);
    } else if (bid < NB_W1 + NB_W2 + NB_W3 + NB_W4 + NB_X0) {
        x0_body(nre, nim, labels, emb, x0bf,
                (bid - NB_W1 - NB_W2 - NB_W3 - NB_W4) * 256 + threadIdx.x);
    } else {
        int idx = (bid - NB_W1 - NB_W2 - NB_W3 - NB_W4 - NB_X0) * 256 + threadIdx.x;
        if (idx < 35840) Szero[idx] = 0.f;   // 143360 bytes of stat copies
    }
}

// ------- epilogue-stats: lq-shfl pre-reduce -> LDS -> atomics into sharded copy -------
__device__ __forceinline__ void epi_stats_flush(float* red, float* Scopy, int Cn,
                                                int cBaseGlobal, int tid, int lq,
                                                const int* clArr, float* s1,
                                                float* s2, float* sp, int isRe) {
    for (int i = tid; i < 320; i += 256) red[i] = 0.f;
    __syncthreads();
#pragma unroll
    for (int sn = 0; sn < 4; ++sn) {
        s1[sn] += __shfl_xor(s1[sn], 16, 64); s1[sn] += __shfl_xor(s1[sn], 32, 64);
        s2[sn] += __shfl_xor(s2[sn], 16, 64); s2[sn] += __shfl_xor(s2[sn], 32, 64);
        sp[sn] += __shfl_xor(sp[sn], 16, 64); sp[sn] += __shfl_xor(sp[sn], 32, 64);
    }
    if (lq == 0) {
#pragma unroll
        for (int sn = 0; sn < 4; ++sn) {
            int cl = clArr[sn];
            if (isRe) {
                atomicAdd(&red[cl * 5 + 0], s1[sn]);
                atomicAdd(&red[cl * 5 + 2], s2[sn]);
                atomicAdd(&red[cl * 5 + 4], sp[sn]);
            } else {
                atomicAdd(&red[cl * 5 + 1], s1[sn]);
                atomicAdd(&red[cl * 5 + 3], s2[sn]);
            }
        }
    }
    __syncthreads();
    for (int i = tid; i < 320; i += 256) {
        int cl = i / 5, st = i - cl * 5;
        atomicAdd(&Scopy[st * Cn + cBaseGlobal + cl], red[i]);
    }
}

// ---------------- gemm1 -> x1cl (interleaved), + BN1 stats ----------------
__global__ __launch_bounds__(256, 1) void gemm1(
    const bf16* __restrict__ A, const bf16* __restrict__ B,
    const float* __restrict__ b1r, const float* __restrict__ b1i,
    bf16* __restrict__ Y, float* __restrict__ Sstat) {
    __shared__ short As[128][40];
    __shared__ short Bs[128][40];
    const int tid = threadIdx.x;
    const int mBase = blockIdx.x * 128, nBase = blockIdx.y * 128;
    const int wid = tid >> 6, lane = tid & 63;
    const int wm = (wid >> 1) * 64, wn = (wid & 1) * 64;
    const int lm = lane & 15, lq = lane >> 4;

    f32x4 acc[4][4] = {};

    for (int k0 = 0; k0 < 224; k0 += 32) {
#pragma unroll
        for (int it = 0; it < 2; ++it) {
            int slot = tid + it * 256;
            int row = slot >> 2, kc = (slot & 3) * 8;
            int k = k0 + kc;
            *(uint4*)(&As[row][kc]) = *(const uint4*)(A + (size_t)(mBase + row) * 224 + k);
            *(uint4*)(&Bs[row][kc]) = *(const uint4*)(B + (size_t)(nBase + row) * 224 + k);
        }
        __syncthreads();
        bf16x8 af[4], bfr[4];
#pragma unroll
        for (int s = 0; s < 4; ++s) {
            af[s]  = *(const bf16x8*)(&As[wm + s * 16 + lm][lq * 8]);
            bfr[s] = *(const bf16x8*)(&Bs[wn + s * 16 + lm][lq * 8]);
        }
#pragma unroll
        for (int sm = 0; sm < 4; ++sm)
#pragma unroll
            for (int sn = 0; sn < 4; ++sn)
                acc[sm][sn] = __builtin_amdgcn_mfma_f32_16x16x32_bf16(af[sm], bfr[sn], acc[sm][sn], 0, 0, 0);
        __syncthreads();
    }

    float s1[4] = {}, s2[4] = {}, sp[4] = {};
    int clArr[4];
#pragma unroll
    for (int sn = 0; sn < 4; ++sn) clArr[sn] = (wn + sn * 16 + lm) >> 1;
    const int part = lm & 1;

#pragma unroll
    for (int sm = 0; sm < 4; ++sm) {
#pragma unroll
        for (int v = 0; v < 4; ++v) {
            int m = mBase + wm + sm * 16 + lq * 4 + v;
#pragma unroll
            for (int sn = 0; sn < 4; ++sn) {
                int n = nBase + wn + sn * 16 + lm;
                int c = (n & 1023) >> 1;
                float bias = part ? b1i[c] : b1r[c];
                float val = acc[sm][sn][v] + bias;
                float pv = __shfl_xor(val, 1, 64);
                s1[sn] += val; s2[sn] += val * val;
                if (!part) sp[sn] += val * pv;
                Y[(size_t)m * 16384 + n] = f2b(val);
            }
        }
    }
    int copy = (blockIdx.y * gridDim.x + blockIdx.x) & (NCOPY - 1);
    epi_stats_flush((float*)As, Sstat + (size_t)copy * 5 * C1, C1,
                    (nBase & 1023) >> 1, tid, lq, clArr, s1, s2, sp, !part);
}

// ------- BN apply+ReLU: block-cooperative fold of NCOPY stat copies -> LDS coefs -------
__global__ void bn_apply_v3(bf16* __restrict__ Y, const float* __restrict__ Scopies,
                            const float* __restrict__ grr, const float* __restrict__ gri,
                            const float* __restrict__ gii,
                            const float* __restrict__ betar, const float* __restrict__ betai,
                            int C, int total8, float invN) {
    __shared__ float coefs[6][512];
    for (int c = threadIdx.x; c < C; c += 256) {
        float sr = 0, si = 0, srr = 0, sii = 0, sri = 0;
        for (int cp = 0; cp < NCOPY; ++cp) {
            const float* S = Scopies + (size_t)cp * 5 * C;
            sr += S[c]; si += S[C + c]; srr += S[2 * C + c]; sii += S[3 * C + c]; sri += S[4 * C + c];
        }
        float mr = sr * invN, mi = si * invN;
        float crr = srr * invN - mr * mr + EPS;
        float cii = sii * invN - mi * mi + EPS;
        float cri = sri * invN - mr * mi;
        float s = sqrtf(crr * cii - cri * cri);
        float t = sqrtf(crr + cii + 2.f * s);
        float inv = 1.f / (s * t);
        float rrr = (cii + s) * inv, rii = (crr + s) * inv, rri = -cri * inv;
        float Grr = grr[c], Gri = gri[c], Gii = gii[c];
        float arr = Grr * rrr + Gri * rri, ari = Grr * rri + Gri * rii;
        float air = Gri * rrr + Gii * rri, aii = Gri * rri + Gii * rii;
        coefs[0][c] = arr; coefs[1][c] = ari;
        coefs[2][c] = betar[c] - arr * mr - ari * mi;
        coefs[3][c] = air; coefs[4][c] = aii;
        coefs[5][c] = betai[c] - air * mr - aii * mi;
    }
    __syncthreads();
    int idx = blockIdx.x * 256 + threadIdx.x;
    if (idx >= total8) return;
    size_t base = (size_t)idx * 8;
    int c0 = ((int)(base & (size_t)(2 * C - 1))) >> 1;
    bf16x8 v8 = *(const bf16x8*)(Y + base);
    bf16x8 o8;
#pragma unroll
    for (int u = 0; u < 4; ++u) {
        int c = c0 + u;
        float vr = s2f(v8[2 * u]), vi = s2f(v8[2 * u + 1]);
        o8[2 * u]     = f2s(fmaxf(coefs[0][c] * vr + coefs[1][c] * vi + coefs[2][c], 0.f));
        o8[2 * u + 1] = f2s(fmaxf(coefs[3][c] * vr + coefs[4][c] * vi + coefs[5][c], 0.f));
    }
    *(bf16x8*)(Y + base) = o8;
}

// ---------------- MFMA GEMM 128x128, LDS-staged A (dbuf, 1 barrier), direct B panels ----------------
template<int CIN, int S, int N>
__global__ __launch_bounds__(256, 4) void gemm_convt_bd(
    const bf16* __restrict__ X, const bf16* __restrict__ Wall,
    const float* __restrict__ biasr, const float* __restrict__ biasi,
    bf16* __restrict__ Y, float* __restrict__ Sstat) {
    constexpr int TWOK = 8 * CIN, C2I = 2 * CIN, C2O = 2 * N, HOUT = 2 * S;
    constexpr int NSTEP = TWOK / 32;
    constexpr int CPS = C2I / 32;
    constexpr int LOG_CPS = (CIN == 512) ? 5 : 4;
    __shared__ short As[2][128][40];
    const int cls = blockIdx.z;
    const int py = cls >> 1, px = cls & 1;
    const int tid = threadIdx.x;
    const int mBase = blockIdx.x * 128, nBase = blockIdx.y * 128;
    const int wid = tid >> 6, lane = tid & 63;
    const int wm = (wid >> 1) * 64, wn = (wid & 1) * 64;
    const int lm = lane & 15, lq = lane >> 4;
    const int dh0 = py ? 1 : 0, dh1 = py ? 0 : -1;
    const int dw0 = px ? 1 : 0, dw1 = px ? 0 : -1;

    const bf16* Wp = Wall
        + ((size_t)(cls * (C2O / 128) + blockIdx.y) * (TWOK / 32)) * 4096
        + ((wn >> 6) * 4) * 512 + lane * 8;

    int rowA[2], kcA[2];
    long offT[2][4];
#pragma unroll
    for (int it = 0; it < 2; ++it) {
        int slot = tid + it * 256;
        rowA[it] = slot >> 2; kcA[it] = (slot & 3) * 8;
        int m = mBase + rowA[it];
        int b = m / (S * S); int rem = m - b * (S * S);
        int i = rem / S, j = rem % S;
#pragma unroll
        for (int t = 0; t < 4; ++t) {
            int a = t >> 1, e = t & 1;
            int ih = i + (a ? dh1 : dh0);
            int iw = j + (e ? dw1 : dw0);
            offT[it][t] = ((unsigned)ih < (unsigned)S && (unsigned)iw < (unsigned)S)
                ? (long)((b * S + ih) * S + iw) * C2I : -1L;
        }
    }

    auto loadA = [&](int kb, uint4* av) {
        int t = kb >> LOG_CPS;
        int q0 = (kb & (CPS - 1)) << 5;
#pragma unroll
        for (int it = 0; it < 2; ++it) {
            long o = offT[it][t];
            uint4 v = {0u, 0u, 0u, 0u};
            if (o >= 0)
                v = *(const uint4*)(X + o + q0 + kcA[it]);
            av[it] = v;
        }
    };

    f32x4 acc[4][4] = {};
    bf16x8 bq[4];
#pragma unroll
    for (int sn = 0; sn < 4; ++sn) bq[sn] = *(const bf16x8*)(Wp + sn * 512);

    {
        uint4 av[2];
        loadA(0, av);
#pragma unroll
        for (int it = 0; it < 2; ++it) *(uint4*)(&As[0][rowA[it]][kcA[it]]) = av[it];
    }
    __syncthreads();

    for (int ks = 0; ks < NSTEP; ++ks) {
        const int cur = ks & 1;
        uint4 av[2];
        if (ks + 1 < NSTEP) loadA(ks + 1, av);
        bf16x8 bcur[4];
#pragma unroll
        for (int sn = 0; sn < 4; ++sn) bcur[sn] = bq[sn];
        if (ks + 1 < NSTEP) {
            const bf16* Wn = Wp + (size_t)(ks + 1) * 4096;
#pragma unroll
            for (int sn = 0; sn < 4; ++sn) bq[sn] = *(const bf16x8*)(Wn + sn * 512);
        }
        bf16x8 af[4];
#pragma unroll
        for (int s = 0; s < 4; ++s)
            af[s] = *(const bf16x8*)(&As[cur][wm + s * 16 + lm][lq * 8]);
#pragma unroll
        for (int sm = 0; sm < 4; ++sm)
#pragma unroll
            for (int sn = 0; sn < 4; ++sn)
                acc[sm][sn] = __builtin_amdgcn_mfma_f32_16x16x32_bf16(af[sm], bcur[sn], acc[sm][sn], 0, 0, 0);
        if (ks + 1 < NSTEP) {
#pragma unroll
            for (int it = 0; it < 2; ++it) *(uint4*)(&As[1 - cur][rowA[it]][kcA[it]]) = av[it];
        }
        __syncthreads();
    }

    float s1[4] = {}, s2[4] = {}, sp[4] = {};
    int clArr[4];
#pragma unroll
    for (int sn = 0; sn < 4; ++sn) clArr[sn] = (wn + sn * 16 + lm) >> 1;
    const int part = lm & 1;

#pragma unroll
    for (int sm = 0; sm < 4; ++sm) {
#pragma unroll
        for (int v = 0; v < 4; ++v) {
            int m = mBase + wm + sm * 16 + lq * 4 + v;
            int b = m / (S * S); int rem = m - b * (S * S);
            int i = rem / S, j = rem % S;
            int oh = 2 * i + py, ow = 2 * j + px;
            size_t rowoff = (size_t)((b * HOUT + oh) * HOUT + ow) * C2O;
#pragma unroll
            for (int sn = 0; sn < 4; ++sn) {
                int n = nBase + wn + sn * 16 + lm;
                int c = n >> 1;
                float bias = part ? biasi[c] : biasr[c];
                float val = acc[sm][sn][v] + bias;
                float pv = __shfl_xor(val, 1, 64);
                s1[sn] += val; s2[sn] += val * val;
                if (!part) sp[sn] += val * pv;
                Y[rowoff + n] = f2b(val);
            }
        }
    }
    int copy = ((blockIdx.z * gridDim.y + blockIdx.y) * gridDim.x + blockIdx.x) & (NCOPY - 1);
    epi_stats_flush((float*)As, Sstat + (size_t)copy * 5 * N, N,
                    nBase >> 1, tid, lq, clArr, s1, s2, sp, !part);
}

// ---------------- layer4 via MFMA, M-tile 256, LDS-staged ----------------
__global__ __launch_bounds__(256, 2) void conv4_mfma(
    const bf16* __restrict__ X, const bf16* __restrict__ Wall,
    const float* __restrict__ br, float* __restrict__ out) {
    constexpr int S = 16, TWOK = 1024, C2I = 256;
    __shared__ short As[256][40];
    __shared__ short Bs[16][40];
    const int cls = blockIdx.z;
    const int py = cls >> 1, px = cls & 1;
    const bf16* W = Wall + (size_t)cls * 16 * TWOK;
    const int tid = threadIdx.x;
    const int mBase = blockIdx.x * 256;
    const int wid = tid >> 6, lane = tid & 63;
    const int wm = wid * 64;
    const int lm = lane & 15, lq = lane >> 4;
    const int dh0 = py ? 1 : 0, dh1 = py ? 0 : -1;
    const int dw0 = px ? 1 : 0, dw1 = px ? 0 : -1;

    int rowA[4], kcA[4];
    long offT[4][4];
#pragma unroll
    for (int it = 0; it < 4; ++it) {
        int slot = tid + it * 256;
        rowA[it] = slot >> 2; kcA[it] = (slot & 3) * 8;
        int m = mBase + rowA[it];
        int b = m >> 8; int rem = m & 255;
        int i = rem >> 4, j = rem & 15;
#pragma unroll
        for (int t = 0; t < 4; ++t) {
            int a = t >> 1, e = t & 1;
            int ih = i + (a ? dh1 : dh0);
            int iw = j + (e ? dw1 : dw0);
            offT[it][t] = ((unsigned)ih < (unsigned)S && (unsigned)iw < (unsigned)S)
                ? (long)((b * S + ih) * S + iw) * C2I : -1L;
        }
    }

    f32x4 acc[4] = {};

    for (int kb = 0; kb < TWOK / 32; ++kb) {
        int t = kb >> 3;
        int q0 = (kb & 7) << 5;
#pragma unroll
        for (int it = 0; it < 4; ++it) {
            long o = offT[it][t];
            uint4 v = {0u, 0u, 0u, 0u};
            if (o >= 0)
                v = *(const uint4*)(X + o + q0 + kcA[it]);
            *(uint4*)(&As[rowA[it]][kcA[it]]) = v;
        }
        if (tid < 64) {
            int row = tid >> 2, kc = (tid & 3) * 8;
            uint4 w = *(const uint4*)(W + (size_t)row * TWOK + kb * 32 + kc);
            *(uint4*)(&Bs[row][kc]) = w;
        }
        __syncthreads();
        bf16x8 bfr = *(const bf16x8*)(&Bs[lm][lq * 8]);
#pragma unroll
        for (int s = 0; s < 4; ++s) {
            bf16x8 af = *(const bf16x8*)(&As[wm + s * 16 + lm][lq * 8]);
            acc[s] = __builtin_amdgcn_mfma_f32_16x16x32_bf16(af, bfr, acc[s], 0, 0, 0);
        }
        __syncthreads();
    }

    int n = lm;
    if (n < NCH) {
        float bias = br[n];
#pragma unroll
        for (int s = 0; s < 4; ++s) {
#pragma unroll
            for (int v = 0; v < 4; ++v) {
                int m = mBase + wm + s * 16 + lq * 4 + v;
                int b = m >> 8; int rem = m & 255;
                int i = rem >> 4, j = rem & 15;
                int oh = 2 * i + py, ow = 2 * j + px;
                out[((size_t)(b * NCH + n) * 32 + oh) * 32 + ow] = tanhf(acc[s][v] + bias);
            }
        }
    }
}

extern "C" void kernel_launch(void* const* d_in, const int* in_sizes, int n_in,
                              void* d_out, int out_size, void* d_ws, size_t ws_size,
                              hipStream_t stream) {
    const float* noise_re = (const float*)d_in[0];
    const float* noise_im = (const float*)d_in[1];
    const int*   labels   = (const int*)d_in[2];
    const float* emb      = (const float*)d_in[3];
    const float* w1r = (const float*)d_in[4],  *w1i = (const float*)d_in[5];
    const float* b1r = (const float*)d_in[6],  *b1i = (const float*)d_in[7];
    const float* g1rr = (const float*)d_in[8], *g1ri = (const float*)d_in[9], *g1ii = (const float*)d_in[10];
    const float* n1br = (const float*)d_in[11], *n1bi = (const float*)d_in[12];
    const float* w2r = (const float*)d_in[13], *w2i = (const float*)d_in[14];
    const float* b2r = (const float*)d_in[15], *b2i = (const float*)d_in[16];
    const float* g2rr = (const float*)d_in[17], *g2ri = (const float*)d_in[18], *g2ii = (const float*)d_in[19];
    const float* n2br = (const float*)d_in[20], *n2bi = (const float*)d_in[21];
    const float* w3r = (const float*)d_in[22], *w3i = (const float*)d_in[23];
    const float* b3r = (const float*)d_in[24], *b3i = (const float*)d_in[25];
    const float* g3rr = (const float*)d_in[26], *g3ri = (const float*)d_in[27], *g3ii = (const float*)d_in[28];
    const float* n3br = (const float*)d_in[29], *n3bi = (const float*)d_in[30];
    const float* w4r = (const float*)d_in[31], *w4i = (const float*)d_in[32];
    const float* b4r = (const float*)d_in[33], *b4i = (const float*)d_in[34];

    // ---- workspace layout (bytes) ---- (same as R18)
    char* ws = (char*)d_ws;
    bf16* y3cl = (bf16*)ws;
    bf16* x1cl = (bf16*)ws;
    bf16* B1    = (bf16*)(ws + 8388608);
    bf16* W2all = (bf16*)(ws + 15728640);
    bf16* y2cl  = (bf16*)(ws + 33554432);
    bf16* W3all = (bf16*)(ws + 50331648);
    bf16* x0bf  = (bf16*)(ws + 54547456);
    bf16* W4all = (bf16*)(ws + 54662144);
    float* S1 = (float*)(ws + 54793216);
    float* S2 = (float*)(ws + 54875136);
    float* S3 = (float*)(ws + 54916096);

    prep_combined<<<NB_W1 + NB_W2 + NB_W3 + NB_W4 + NB_X0 + NB_Z, 256, 0, stream>>>(
        w1r, w1i, w2r, w2i, w3r, w3i, w4r, w4i,
        noise_re, noise_im, labels, emb,
        B1, W2all, W3all, W4all, x0bf, S1);

    // L1 GEMM (+BN1 stats, sharded) -> x1cl
    gemm1<<<dim3(2, 128), 256, 0, stream>>>(x0bf, B1, b1r, b1i, x1cl, S1);
    bn_apply_v3<<<2048, 256, 0, stream>>>(x1cl, S1, g1rr, g1ri, g1ii, n1br, n1bi,
                                          C1, 524288, 1.f / 4096.f);

    // L2 GEMM (+BN2 stats) -> y2cl
    gemm_convt_bd<C1, 4, C2><<<dim3(32, 4, 4), 256, 0, stream>>>(x1cl, W2all, b2r, b2i, y2cl, S2);
    bn_apply_v3<<<4096, 256, 0, stream>>>(y2cl, S2, g2rr, g2ri, g2ii, n2br, n2bi,
                                          C2, 1048576, 1.f / 16384.f);

    // L3 GEMM (+BN3 stats) -> y3cl
    gemm_convt_bd<C2, 8, C3><<<dim3(128, 2, 4), 256, 0, stream>>>(y2cl, W3all, b3r, b3i, y3cl, S3);
    bn_apply_v3<<<8192, 256, 0, stream>>>(y3cl, S3, g3rr, g3ri, g3ii, n3br, n3bi,
                                          C3, 2097152, 1.f / 65536.f);

    // L4: MFMA + tanh -> d_out (real part, fp32), M-tile 256
    conv4_mfma<<<dim3(256, 1, 4), 256, 0, stream>>>(y3cl, W4all, b4r, (float*)d_out);
}

// Round 21
// 463.580 us; speedup vs baseline: 2.8084x; 2.8084x over previous
//
#include <hip/hip_runtime.h>
#include <hip/hip_bf16.h>
#include <math.h>

#define BATCH 256
#define LAT 100
#define NCLS 10
#define CIN0 110
#define C1 512
#define C2 256
#define C3 128
#define NCH 3
#define EPS 1e-5f
#define NCOPY 8

typedef __hip_bfloat16 bf16;
typedef short bf16x8 __attribute__((ext_vector_type(8)));
typedef float f32x4 __attribute__((ext_vector_type(4)));

__device__ __forceinline__ float b2f(bf16 v) { return __bfloat162float(v); }
__device__ __forceinline__ bf16 f2b(float v) { return __float2bfloat16(v); }
__device__ __forceinline__ float s2f(short s) {
    unsigned u = ((unsigned)(unsigned short)s) << 16;
    return __builtin_bit_cast(float, u);
}
__device__ __forceinline__ short f2s(float f) {
    bf16 b = __float2bfloat16(f);
    return *(short*)&b;
}

// ======== INTERLEAVED complex channel layout everywhere ========
#define NB_W1 14336
#define NB_W2 32768
#define NB_W3 8192
#define NB_W4 256
#define NB_X0 224
#define NB_Z  36     // zero the stat copies (143360 B)

__device__ __forceinline__ void w1prep_body(const float* wr, const float* wi, bf16* B, int idx) {
    if (idx >= 16384 * 224) return;
    int n = idx / 224, k = idx - n * 224;
    int p = n >> 10;
    int c = (n & 1023) >> 1;
    int part = n & 1;
    int pk = k >= 112; int ci = k - pk * 112;
    float v = 0.f;
    if (ci < CIN0) {
        size_t widx = ((size_t)ci * C1 + c) * 16 + p;
        float vr = wr[widx], vi = wi[widx];
        v = (part == 0) ? (pk ? -vi : vr) : (pk ? vr : vi);
    }
    B[idx] = f2b(v);
}

template<int CIN, int N>
__device__ __forceinline__ void wprep_panel_body(const float* wr, const float* wi, bf16* W,
                                                 size_t idx) {
    constexpr int TWOK = 8 * CIN, C2I = 2 * CIN;
    size_t per_cls = (size_t)2 * N * TWOK;
    if (idx >= 4 * per_cls) return;
    int cls = (int)(idx / per_cls);
    size_t r = idx - (size_t)cls * per_cls;
    size_t chunk_nb = (size_t)TWOK * 128;
    int nb = (int)(r / chunk_nb);
    int r2 = (int)(r - (size_t)nb * chunk_nb);
    int kb = r2 >> 12;
    int w = r2 & 4095;
    int f = w >> 9;
    int l = (w >> 3) & 63;
    int j = w & 7;
    int n_virt = nb * 128 + (f >> 2) * 64 + (f & 3) * 16 + (l & 15);
    int k = kb * 32 + (l >> 4) * 8 + j;
    int c = n_virt >> 1, part = n_virt & 1;
    int t = k / C2I;
    int q = k & (C2I - 1);
    int ci = q >> 1, p = q & 1;
    int py = cls >> 1, px = cls & 1;
    int a = t >> 1, e = t & 1;
    int kh = py ? (a ? 2 : 0) : (a ? 3 : 1);
    int kw = px ? (e ? 2 : 0) : (e ? 3 : 1);
    size_t widx = ((size_t)ci * N + c) * 16 + kh * 4 + kw;
    float vr = wr[widx], vi = wi[widx];
    float v = (part == 0) ? (p ? -vi : vr) : (p ? vr : vi);
    W[idx] = f2b(v);
}

__device__ __forceinline__ void wprep4_body(const float* wr, const float* wi, bf16* W, int idx) {
    if (idx >= 65536) return;
    int cls = idx >> 14, rem = idx & 16383;
    int py = cls >> 1, px = cls & 1;
    int n = rem >> 10, k = rem & 1023;
    float v = 0.f;
    if (n < NCH) {
        int t = k >> 8, q = k & 255;
        int ci = q >> 1, p = q & 1;
        int a = t >> 1, e = t & 1;
        int kh = py ? (a ? 2 : 0) : (a ? 3 : 1);
        int kw = px ? (e ? 2 : 0) : (e ? 3 : 1);
        size_t widx = ((size_t)ci * NCH + n) * 16 + kh * 4 + kw;
        v = p ? -wi[widx] : wr[widx];
    }
    W[idx] = f2b(v);
}

__device__ __forceinline__ void x0_body(const float* nre, const float* nim,
                                        const int* labels, const float* emb,
                                        bf16* A, int idx) {
    if (idx >= BATCH * 224) return;
    int b = idx / 224, k = idx - b * 224;
    int p = k >= 112; int ci = k - p * 112;
    float v = 0.f;
    if (ci < CIN0) {
        if (!p) v = (ci < LAT) ? nre[b * LAT + ci] : emb[labels[b] * NCLS + (ci - LAT)];
        else    v = (ci < LAT) ? nim[b * LAT + ci] : 0.f;
    }
    A[idx] = f2b(v);
}

__global__ void prep_combined(const float* __restrict__ w1r, const float* __restrict__ w1i,
                              const float* __restrict__ w2r, const float* __restrict__ w2i,
                              const float* __restrict__ w3r, const float* __restrict__ w3i,
                              const float* __restrict__ w4r, const float* __restrict__ w4i,
                              const float* __restrict__ nre, const float* __restrict__ nim,
                              const int* __restrict__ labels, const float* __restrict__ emb,
                              bf16* __restrict__ B1, bf16* __restrict__ W2all,
                              bf16* __restrict__ W3all, bf16* __restrict__ W4all,
                              bf16* __restrict__ x0bf, float* __restrict__ Szero) {
    int bid = blockIdx.x;
    if (bid < NB_W1) {
        w1prep_body(w1r, w1i, B1, bid * 256 + threadIdx.x);
    } else if (bid < NB_W1 + NB_W2) {
        wprep_panel_body<C1, C2>(w2r, w2i, W2all, (size_t)(bid - NB_W1) * 256 + threadIdx.x);
    } else if (bid < NB_W1 + NB_W2 + NB_W3) {
        wprep_panel_body<C2, C3>(w3r, w3i, W3all, (size_t)(bid - NB_W1 - NB_W2) * 256 + threadIdx.x);
    } else if (bid < NB_W1 + NB_W2 + NB_W3 + NB_W4) {
        wprep4_body(w4r, w4i, W4all, (bid - NB_W1 - NB_W2 - NB_W3) * 256 + threadIdx.x);
    } else if (bid < NB_W1 + NB_W2 + NB_W3 + NB_W4 + NB_X0) {
        x0_body(nre, nim, labels, emb, x0bf,
                (bid - NB_W1 - NB_W2 - NB_W3 - NB_W4) * 256 + threadIdx.x);
    } else {
        int idx = (bid - NB_W1 - NB_W2 - NB_W3 - NB_W4 - NB_X0) * 256 + threadIdx.x;
        if (idx < 35840) Szero[idx] = 0.f;   // 143360 bytes of stat copies
    }
}

// ------- epilogue-stats: lq-shfl pre-reduce -> LDS -> atomics into sharded copy -------
__device__ __forceinline__ void epi_stats_flush(float* red, float* Scopy, int Cn,
                                                int cBaseGlobal, int tid, int lq,
                                                const int* clArr, float* s1,
                                                float* s2, float* sp, int isRe) {
    for (int i = tid; i < 320; i += 256) red[i] = 0.f;
    __syncthreads();
#pragma unroll
    for (int sn = 0; sn < 4; ++sn) {
        s1[sn] += __shfl_xor(s1[sn], 16, 64); s1[sn] += __shfl_xor(s1[sn], 32, 64);
        s2[sn] += __shfl_xor(s2[sn], 16, 64); s2[sn] += __shfl_xor(s2[sn], 32, 64);
        sp[sn] += __shfl_xor(sp[sn], 16, 64); sp[sn] += __shfl_xor(sp[sn], 32, 64);
    }
    if (lq == 0) {
#pragma unroll
        for (int sn = 0; sn < 4; ++sn) {
            int cl = clArr[sn];
            if (isRe) {
                atomicAdd(&red[cl * 5 + 0], s1[sn]);
                atomicAdd(&red[cl * 5 + 2], s2[sn]);
                atomicAdd(&red[cl * 5 + 4], sp[sn]);
            } else {
                atomicAdd(&red[cl * 5 + 1], s1[sn]);
                atomicAdd(&red[cl * 5 + 3], s2[sn]);
            }
        }
    }
    __syncthreads();
    for (int i = tid; i < 320; i += 256) {
        int cl = i / 5, st = i - cl * 5;
        atomicAdd(&Scopy[st * Cn + cBaseGlobal + cl], red[i]);
    }
}

// ---------------- gemm1 -> x1cl (interleaved), + BN1 stats ----------------
__global__ __launch_bounds__(256, 1) void gemm1(
    const bf16* __restrict__ A, const bf16* __restrict__ B,
    const float* __restrict__ b1r, const float* __restrict__ b1i,
    bf16* __restrict__ Y, float* __restrict__ Sstat) {
    __shared__ short As[128][40];
    __shared__ short Bs[128][40];
    const int tid = threadIdx.x;
    const int mBase = blockIdx.x * 128, nBase = blockIdx.y * 128;
    const int wid = tid >> 6, lane = tid & 63;
    const int wm = (wid >> 1) * 64, wn = (wid & 1) * 64;
    const int lm = lane & 15, lq = lane >> 4;

    f32x4 acc[4][4] = {};

    for (int k0 = 0; k0 < 224; k0 += 32) {
#pragma unroll
        for (int it = 0; it < 2; ++it) {
            int slot = tid + it * 256;
            int row = slot >> 2, kc = (slot & 3) * 8;
            int k = k0 + kc;
            *(uint4*)(&As[row][kc]) = *(const uint4*)(A + (size_t)(mBase + row) * 224 + k);
            *(uint4*)(&Bs[row][kc]) = *(const uint4*)(B + (size_t)(nBase + row) * 224 + k);
        }
        __syncthreads();
        bf16x8 af[4], bfr[4];
#pragma unroll
        for (int s = 0; s < 4; ++s) {
            af[s]  = *(const bf16x8*)(&As[wm + s * 16 + lm][lq * 8]);
            bfr[s] = *(const bf16x8*)(&Bs[wn + s * 16 + lm][lq * 8]);
        }
#pragma unroll
        for (int sm = 0; sm < 4; ++sm)
#pragma unroll
            for (int sn = 0; sn < 4; ++sn)
                acc[sm][sn] = __builtin_amdgcn_mfma_f32_16x16x32_bf16(af[sm], bfr[sn], acc[sm][sn], 0, 0, 0);
        __syncthreads();
    }

    float s1[4] = {}, s2[4] = {}, sp[4] = {};
    int clArr[4];
#pragma unroll
    for (int sn = 0; sn < 4; ++sn) clArr[sn] = (wn + sn * 16 + lm) >> 1;
    const int part = lm & 1;

#pragma unroll
    for (int sm = 0; sm < 4; ++sm) {
#pragma unroll
        for (int v = 0; v < 4; ++v) {
            int m = mBase + wm + sm * 16 + lq * 4 + v;
#pragma unroll
            for (int sn = 0; sn < 4; ++sn) {
                int n = nBase + wn + sn * 16 + lm;
                int c = (n & 1023) >> 1;
                float bias = part ? b1i[c] : b1r[c];
                float val = acc[sm][sn][v] + bias;
                float pv = __shfl_xor(val, 1, 64);
                s1[sn] += val; s2[sn] += val * val;
                if (!part) sp[sn] += val * pv;
                Y[(size_t)m * 16384 + n] = f2b(val);
            }
        }
    }
    int copy = (blockIdx.y * gridDim.x + blockIdx.x) & (NCOPY - 1);
    epi_stats_flush((float*)As, Sstat + (size_t)copy * 5 * C1, C1,
                    (nBase & 1023) >> 1, tid, lq, clArr, s1, s2, sp, !part);
}

// ------- BN apply+ReLU: block-cooperative fold of NCOPY stat copies -> LDS coefs -------
__global__ void bn_apply_v3(bf16* __restrict__ Y, const float* __restrict__ Scopies,
                            const float* __restrict__ grr, const float* __restrict__ gri,
                            const float* __restrict__ gii,
                            const float* __restrict__ betar, const float* __restrict__ betai,
                            int C, int total8, float invN) {
    __shared__ float coefs[6][512];
    for (int c = threadIdx.x; c < C; c += 256) {
        float sr = 0, si = 0, srr = 0, sii = 0, sri = 0;
        for (int cp = 0; cp < NCOPY; ++cp) {
            const float* S = Scopies + (size_t)cp * 5 * C;
            sr += S[c]; si += S[C + c]; srr += S[2 * C + c]; sii += S[3 * C + c]; sri += S[4 * C + c];
        }
        float mr = sr * invN, mi = si * invN;
        float crr = srr * invN - mr * mr + EPS;
        float cii = sii * invN - mi * mi + EPS;
        float cri = sri * invN - mr * mi;
        float s = sqrtf(crr * cii - cri * cri);
        float t = sqrtf(crr + cii + 2.f * s);
        float inv = 1.f / (s * t);
        float rrr = (cii + s) * inv, rii = (crr + s) * inv, rri = -cri * inv;
        float Grr = grr[c], Gri = gri[c], Gii = gii[c];
        float arr = Grr * rrr + Gri * rri, ari = Grr * rri + Gri * rii;
        float air = Gri * rrr + Gii * rri, aii = Gri * rri + Gii * rii;
        coefs[0][c] = arr; coefs[1][c] = ari;
        coefs[2][c] = betar[c] - arr * mr - ari * mi;
        coefs[3][c] = air; coefs[4][c] = aii;
        coefs[5][c] = betai[c] - air * mr - aii * mi;
    }
    __syncthreads();
    int idx = blockIdx.x * 256 + threadIdx.x;
    if (idx >= total8) return;
    size_t base = (size_t)idx * 8;
    int c0 = ((int)(base & (size_t)(2 * C - 1))) >> 1;
    bf16x8 v8 = *(const bf16x8*)(Y + base);
    bf16x8 o8;
#pragma unroll
    for (int u = 0; u < 4; ++u) {
        int c = c0 + u;
        float vr = s2f(v8[2 * u]), vi = s2f(v8[2 * u + 1]);
        o8[2 * u]     = f2s(fmaxf(coefs[0][c] * vr + coefs[1][c] * vi + coefs[2][c], 0.f));
        o8[2 * u + 1] = f2s(fmaxf(coefs[3][c] * vr + coefs[4][c] * vi + coefs[5][c], 0.f));
    }
    *(bf16x8*)(Y + base) = o8;
}

// ---------------- MFMA GEMM 128x128, LDS-staged A (dbuf, 1 barrier), direct B panels ----------------
// __launch_bounds__(256, 2): (256,4) in R20 forced VGPR 72->64 and spilled the
// accumulator tile to scratch (WRITE_SIZE 34.7MB -> 416MB, gemm 105 -> 532 us).
template<int CIN, int S, int N>
__global__ __launch_bounds__(256, 2) void gemm_convt_bd(
    const bf16* __restrict__ X, const bf16* __restrict__ Wall,
    const float* __restrict__ biasr, const float* __restrict__ biasi,
    bf16* __restrict__ Y, float* __restrict__ Sstat) {
    constexpr int TWOK = 8 * CIN, C2I = 2 * CIN, C2O = 2 * N, HOUT = 2 * S;
    constexpr int NSTEP = TWOK / 32;
    constexpr int CPS = C2I / 32;
    constexpr int LOG_CPS = (CIN == 512) ? 5 : 4;
    __shared__ short As[2][128][40];
    const int cls = blockIdx.z;
    const int py = cls >> 1, px = cls & 1;
    const int tid = threadIdx.x;
    const int mBase = blockIdx.x * 128, nBase = blockIdx.y * 128;
    const int wid = tid >> 6, lane = tid & 63;
    const int wm = (wid >> 1) * 64, wn = (wid & 1) * 64;
    const int lm = lane & 15, lq = lane >> 4;
    const int dh0 = py ? 1 : 0, dh1 = py ? 0 : -1;
    const int dw0 = px ? 1 : 0, dw1 = px ? 0 : -1;

    const bf16* Wp = Wall
        + ((size_t)(cls * (C2O / 128) + blockIdx.y) * (TWOK / 32)) * 4096
        + ((wn >> 6) * 4) * 512 + lane * 8;

    int rowA[2], kcA[2];
    long offT[2][4];
#pragma unroll
    for (int it = 0; it < 2; ++it) {
        int slot = tid + it * 256;
        rowA[it] = slot >> 2; kcA[it] = (slot & 3) * 8;
        int m = mBase + rowA[it];
        int b = m / (S * S); int rem = m - b * (S * S);
        int i = rem / S, j = rem % S;
#pragma unroll
        for (int t = 0; t < 4; ++t) {
            int a = t >> 1, e = t & 1;
            int ih = i + (a ? dh1 : dh0);
            int iw = j + (e ? dw1 : dw0);
            offT[it][t] = ((unsigned)ih < (unsigned)S && (unsigned)iw < (unsigned)S)
                ? (long)((b * S + ih) * S + iw) * C2I : -1L;
        }
    }

    auto loadA = [&](int kb, uint4* av) {
        int t = kb >> LOG_CPS;
        int q0 = (kb & (CPS - 1)) << 5;
#pragma unroll
        for (int it = 0; it < 2; ++it) {
            long o = offT[it][t];
            uint4 v = {0u, 0u, 0u, 0u};
            if (o >= 0)
                v = *(const uint4*)(X + o + q0 + kcA[it]);
            av[it] = v;
        }
    };

    f32x4 acc[4][4] = {};
    bf16x8 bq[4];
#pragma unroll
    for (int sn = 0; sn < 4; ++sn) bq[sn] = *(const bf16x8*)(Wp + sn * 512);

    {
        uint4 av[2];
        loadA(0, av);
#pragma unroll
        for (int it = 0; it < 2; ++it) *(uint4*)(&As[0][rowA[it]][kcA[it]]) = av[it];
    }
    __syncthreads();

    for (int ks = 0; ks < NSTEP; ++ks) {
        const int cur = ks & 1;
        uint4 av[2];
        if (ks + 1 < NSTEP) loadA(ks + 1, av);
        bf16x8 bcur[4];
#pragma unroll
        for (int sn = 0; sn < 4; ++sn) bcur[sn] = bq[sn];
        if (ks + 1 < NSTEP) {
            const bf16* Wn = Wp + (size_t)(ks + 1) * 4096;
#pragma unroll
            for (int sn = 0; sn < 4; ++sn) bq[sn] = *(const bf16x8*)(Wn + sn * 512);
        }
        bf16x8 af[4];
#pragma unroll
        for (int s = 0; s < 4; ++s)
            af[s] = *(const bf16x8*)(&As[cur][wm + s * 16 + lm][lq * 8]);
#pragma unroll
        for (int sm = 0; sm < 4; ++sm)
#pragma unroll
            for (int sn = 0; sn < 4; ++sn)
                acc[sm][sn] = __builtin_amdgcn_mfma_f32_16x16x32_bf16(af[sm], bcur[sn], acc[sm][sn], 0, 0, 0);
        if (ks + 1 < NSTEP) {
#pragma unroll
            for (int it = 0; it < 2; ++it) *(uint4*)(&As[1 - cur][rowA[it]][kcA[it]]) = av[it];
        }
        __syncthreads();
    }

    float s1[4] = {}, s2[4] = {}, sp[4] = {};
    int clArr[4];
#pragma unroll
    for (int sn = 0; sn < 4; ++sn) clArr[sn] = (wn + sn * 16 + lm) >> 1;
    const int part = lm & 1;

#pragma unroll
    for (int sm = 0; sm < 4; ++sm) {
#pragma unroll
        for (int v = 0; v < 4; ++v) {
            int m = mBase + wm + sm * 16 + lq * 4 + v;
            int b = m / (S * S); int rem = m - b * (S * S);
            int i = rem / S, j = rem % S;
            int oh = 2 * i + py, ow = 2 * j + px;
            size_t rowoff = (size_t)((b * HOUT + oh) * HOUT + ow) * C2O;
#pragma unroll
            for (int sn = 0; sn < 4; ++sn) {
                int n = nBase + wn + sn * 16 + lm;
                int c = n >> 1;
                float bias = part ? biasi[c] : biasr[c];
                float val = acc[sm][sn][v] + bias;
                float pv = __shfl_xor(val, 1, 64);
                s1[sn] += val; s2[sn] += val * val;
                if (!part) sp[sn] += val * pv;
                Y[rowoff + n] = f2b(val);
            }
        }
    }
    int copy = ((blockIdx.z * gridDim.y + blockIdx.y) * gridDim.x + blockIdx.x) & (NCOPY - 1);
    epi_stats_flush((float*)As, Sstat + (size_t)copy * 5 * N, N,
                    nBase >> 1, tid, lq, clArr, s1, s2, sp, !part);
}

// ---------------- layer4 via MFMA, M-tile 256, LDS-staged ----------------
__global__ __launch_bounds__(256, 2) void conv4_mfma(
    const bf16* __restrict__ X, const bf16* __restrict__ Wall,
    const float* __restrict__ br, float* __restrict__ out) {
    constexpr int S = 16, TWOK = 1024, C2I = 256;
    __shared__ short As[256][40];
    __shared__ short Bs[16][40];
    const int cls = blockIdx.z;
    const int py = cls >> 1, px = cls & 1;
    const bf16* W = Wall + (size_t)cls * 16 * TWOK;
    const int tid = threadIdx.x;
    const int mBase = blockIdx.x * 256;
    const int wid = tid >> 6, lane = tid & 63;
    const int wm = wid * 64;
    const int lm = lane & 15, lq = lane >> 4;
    const int dh0 = py ? 1 : 0, dh1 = py ? 0 : -1;
    const int dw0 = px ? 1 : 0, dw1 = px ? 0 : -1;

    int rowA[4], kcA[4];
    long offT[4][4];
#pragma unroll
    for (int it = 0; it < 4; ++it) {
        int slot = tid + it * 256;
        rowA[it] = slot >> 2; kcA[it] = (slot & 3) * 8;
        int m = mBase + rowA[it];
        int b = m >> 8; int rem = m & 255;
        int i = rem >> 4, j = rem & 15;
#pragma unroll
        for (int t = 0; t < 4; ++t) {
            int a = t >> 1, e = t & 1;
            int ih = i + (a ? dh1 : dh0);
            int iw = j + (e ? dw1 : dw0);
            offT[it][t] = ((unsigned)ih < (unsigned)S && (unsigned)iw < (unsigned)S)
                ? (long)((b * S + ih) * S + iw) * C2I : -1L;
        }
    }

    f32x4 acc[4] = {};

    for (int kb = 0; kb < TWOK / 32; ++kb) {
        int t = kb >> 3;
        int q0 = (kb & 7) << 5;
#pragma unroll
        for (int it = 0; it < 4; ++it) {
            long o = offT[it][t];
            uint4 v = {0u, 0u, 0u, 0u};
            if (o >= 0)
                v = *(const uint4*)(X + o + q0 + kcA[it]);
            *(uint4*)(&As[rowA[it]][kcA[it]]) = v;
        }
        if (tid < 64) {
            int row = tid >> 2, kc = (tid & 3) * 8;
            uint4 w = *(const uint4*)(W + (size_t)row * TWOK + kb * 32 + kc);
            *(uint4*)(&Bs[row][kc]) = w;
        }
        __syncthreads();
        bf16x8 bfr = *(const bf16x8*)(&Bs[lm][lq * 8]);
#pragma unroll
        for (int s = 0; s < 4; ++s) {
            bf16x8 af = *(const bf16x8*)(&As[wm + s * 16 + lm][lq * 8]);
            acc[s] = __builtin_amdgcn_mfma_f32_16x16x32_bf16(af, bfr, acc[s], 0, 0, 0);
        }
        __syncthreads();
    }

    int n = lm;
    if (n < NCH) {
        float bias = br[n];
#pragma unroll
        for (int s = 0; s < 4; ++s) {
#pragma unroll
            for (int v = 0; v < 4; ++v) {
                int m = mBase + wm + s * 16 + lq * 4 + v;
                int b = m >> 8; int rem = m & 255;
                int i = rem >> 4, j = rem & 15;
                int oh = 2 * i + py, ow = 2 * j + px;
                out[((size_t)(b * NCH + n) * 32 + oh) * 32 + ow] = tanhf(acc[s][v] + bias);
            }
        }
    }
}

extern "C" void kernel_launch(void* const* d_in, const int* in_sizes, int n_in,
                              void* d_out, int out_size, void* d_ws, size_t ws_size,
                              hipStream_t stream) {
    const float* noise_re = (const float*)d_in[0];
    const float* noise_im = (const float*)d_in[1];
    const int*   labels   = (const int*)d_in[2];
    const float* emb      = (const float*)d_in[3];
    const float* w1r = (const float*)d_in[4],  *w1i = (const float*)d_in[5];
    const float* b1r = (const float*)d_in[6],  *b1i = (const float*)d_in[7];
    const float* g1rr = (const float*)d_in[8], *g1ri = (const float*)d_in[9], *g1ii = (const float*)d_in[10];
    const float* n1br = (const float*)d_in[11], *n1bi = (const float*)d_in[12];
    const float* w2r = (const float*)d_in[13], *w2i = (const float*)d_in[14];
    const float* b2r = (const float*)d_in[15], *b2i = (const float*)d_in[16];
    const float* g2rr = (const float*)d_in[17], *g2ri = (const float*)d_in[18], *g2ii = (const float*)d_in[19];
    const float* n2br = (const float*)d_in[20], *n2bi = (const float*)d_in[21];
    const float* w3r = (const float*)d_in[22], *w3i = (const float*)d_in[23];
    const float* b3r = (const float*)d_in[24], *b3i = (const float*)d_in[25];
    const float* g3rr = (const float*)d_in[26], *g3ri = (const float*)d_in[27], *g3ii = (const float*)d_in[28];
    const float* n3br = (const float*)d_in[29], *n3bi = (const float*)d_in[30];
    const float* w4r = (const float*)d_in[31], *w4i = (const float*)d_in[32];
    const float* b4r = (const float*)d_in[33], *b4i = (const float*)d_in[34];

    // ---- workspace layout (bytes) ---- (same as R18)
    char* ws = (char*)d_ws;
    bf16* y3cl = (bf16*)ws;
    bf16* x1cl = (bf16*)ws;
    bf16* B1    = (bf16*)(ws + 8388608);
    bf16* W2all = (bf16*)(ws + 15728640);
    bf16* y2cl  = (bf16*)(ws + 33554432);
    bf16* W3all = (bf16*)(ws + 50331648);
    bf16* x0bf  = (bf16*)(ws + 54547456);
    bf16* W4all = (bf16*)(ws + 54662144);
    float* S1 = (float*)(ws + 54793216);
    float* S2 = (float*)(ws + 54875136);
    float* S3 = (float*)(ws + 54916096);

    prep_combined<<<NB_W1 + NB_W2 + NB_W3 + NB_W4 + NB_X0 + NB_Z, 256, 0, stream>>>(
        w1r, w1i, w2r, w2i, w3r, w3i, w4r, w4i,
        noise_re, noise_im, labels, emb,
        B1, W2all, W3all, W4all, x0bf, S1);

    // L1 GEMM (+BN1 stats, sharded) -> x1cl
    gemm1<<<dim3(2, 128), 256, 0, stream>>>(x0bf, B1, b1r, b1i, x1cl, S1);
    bn_apply_v3<<<2048, 256, 0, stream>>>(x1cl, S1, g1rr, g1ri, g1ii, n1br, n1bi,
                                          C1, 524288, 1.f / 4096.f);

    // L2 GEMM (+BN2 stats) -> y2cl
    gemm_convt_bd<C1, 4, C2><<<dim3(32, 4, 4), 256, 0, stream>>>(x1cl, W2all, b2r, b2i, y2cl, S2);
    bn_apply_v3<<<4096, 256, 0, stream>>>(y2cl, S2, g2rr, g2ri, g2ii, n2br, n2bi,
                                          C2, 1048576, 1.f / 16384.f);

    // L3 GEMM (+BN3 stats) -> y3cl
    gemm_convt_bd<C2, 8, C3><<<dim3(128, 2, 4), 256, 0, stream>>>(y2cl, W3all, b3r, b3i, y3cl, S3);
    bn_apply_v3<<<8192, 256, 0, stream>>>(y3cl, S3, g3rr, g3ri, g3ii, n3br, n3bi,
                                          C3, 2097152, 1.f / 65536.f);

    // L4: MFMA + tanh -> d_out (real part, fp32), M-tile 256
    conv4_mfma<<<dim3(256, 1, 4), 256, 0, stream>>>(y3cl, W4all, b4r, (float*)d_out);
}